// Round 1
// baseline (289.962 us; speedup 1.0000x reference)
//
#include <hip/hip_runtime.h>
#include <math.h>

#define B 8
#define NSMI 100
#define NATOM 45
#define ND 145      // NSMI + NATOM
#define NP 1000
#define D 64

// ---------------- kernel 1: shared attention projection ----------------
// grid: B*(NSMI+NP+NATOM) blocks, 64 threads.
// smi_attss[b,0:100,:]   = smi_tf @ w_att + b_att
// smi_attss[b,100:145,:] = drug_gat
// pro_att[b,:,:]         = pro_tf @ w_att + b_att
__global__ void k_proj(const float* __restrict__ smi_tf,
                       const float* __restrict__ pro_tf,
                       const float* __restrict__ drug_gat,
                       const float* __restrict__ w_att,
                       const float* __restrict__ b_att,
                       float* __restrict__ smi_attss,
                       float* __restrict__ pro_att)
{
    __shared__ float row[D];
    int blk = blockIdx.x;
    int b = blk / (NSMI + NP + NATOM);
    int rr = blk - b * (NSMI + NP + NATOM);
    int d = threadIdx.x;
    if (rr < NSMI) {
        row[d] = smi_tf[(b * NSMI + rr) * D + d];
        __syncthreads();
        float acc = b_att[d];
        #pragma unroll
        for (int k = 0; k < D; ++k) acc = fmaf(row[k], w_att[k * D + d], acc);
        smi_attss[(b * ND + rr) * D + d] = acc;
    } else if (rr < NSMI + NP) {
        int j = rr - NSMI;
        row[d] = pro_tf[(b * NP + j) * D + d];
        __syncthreads();
        float acc = b_att[d];
        #pragma unroll
        for (int k = 0; k < D; ++k) acc = fmaf(row[k], w_att[k * D + d], acc);
        pro_att[(b * NP + j) * D + d] = acc;
    } else {
        int a = rr - NSMI - NP;
        smi_attss[(b * ND + NSMI + a) * D + d] = drug_gat[(b * NATOM + a) * D + d];
    }
}

// ---------------- kernel 2a: S_row[b,i,:] = sum_j relu(a_i + p_j) ----------------
// grid: B*ND blocks, 256 threads (4 waves x 64 dims)
__global__ void k_rowsum(const float* __restrict__ smi_attss,
                         const float* __restrict__ pro_att,
                         float* __restrict__ S_row)
{
    __shared__ float red[256];
    int blk = blockIdx.x;
    int b = blk / ND;
    int i = blk - b * ND;
    int t = threadIdx.x;
    int d = t & 63;
    int jj = t >> 6;
    float a = smi_attss[(b * ND + i) * D + d];
    const float* p = pro_att + (size_t)(b * NP) * D + d;
    float acc = 0.f;
    for (int j = jj; j < NP; j += 4)
        acc += fmaxf(0.f, a + p[j * D]);
    red[t] = acc;
    __syncthreads();
    if (t < 64)
        S_row[(b * ND + i) * D + t] = red[t] + red[t + 64] + red[t + 128] + red[t + 192];
}

// ---------------- kernel 2b: S_col[b,j,:] = sum_i relu(a_i + p_j) ----------------
// grid: B*NP blocks, 256 threads
__global__ void k_colsum(const float* __restrict__ smi_attss,
                         const float* __restrict__ pro_att,
                         float* __restrict__ S_col)
{
    __shared__ float red[256];
    int blk = blockIdx.x;
    int b = blk / NP;
    int j = blk - b * NP;
    int t = threadIdx.x;
    int d = t & 63;
    int ii = t >> 6;
    float p = pro_att[(b * NP + j) * D + d];
    const float* a = smi_attss + (size_t)(b * ND) * D + d;
    float acc = 0.f;
    for (int i = ii; i < ND; i += 4)
        acc += fmaxf(0.f, a[i * D] + p);
    red[t] = acc;
    __syncthreads();
    if (t < 64)
        S_col[(b * NP + j) * D + t] = red[t] + red[t + 64] + red[t + 128] + red[t + 192];
}

// ---------------- kernel 3a: smi gate, writes gated row over S_row ----------------
// grid: B*ND blocks, 64 threads.  smi_tfs = smi_attss * (0.5 + sigmoid((S_row/NP)@w_att + b_att))
__global__ void k_gate_smi(const float* __restrict__ smi_attss,
                           const float* __restrict__ w_att,
                           const float* __restrict__ b_att,
                           float* __restrict__ S_row /* in: sums, out: smi_tfs */)
{
    __shared__ float v[D];
    int blk = blockIdx.x;
    int d = threadIdx.x;
    v[d] = S_row[blk * D + d] * (1.0f / NP);
    __syncthreads();
    float m = b_att[d];
    #pragma unroll
    for (int k = 0; k < D; ++k) m = fmaf(v[k], w_att[k * D + d], m);
    float g = 1.f / (1.f + expf(-m));
    S_row[blk * D + d] = smi_attss[blk * D + d] * (0.5f + g);
}

// ---------------- kernel 3b: pro gate, writes gated row over S_col ----------------
// grid: B*NP blocks, 64 threads.  pro_tfs = pro_tf * (0.5 + sigmoid((S_col/ND)@w_att + b_att))
__global__ void k_gate_pro(const float* __restrict__ pro_tf,
                           const float* __restrict__ w_att,
                           const float* __restrict__ b_att,
                           float* __restrict__ S_col /* in: sums, out: pro_tfs */)
{
    __shared__ float v[D];
    int blk = blockIdx.x;
    int d = threadIdx.x;
    v[d] = S_col[blk * D + d] * (1.0f / ND);
    __syncthreads();
    float m = b_att[d];
    #pragma unroll
    for (int k = 0; k < D; ++k) m = fmaf(v[k], w_att[k * D + d], m);
    float g = 1.f / (1.f + expf(-m));
    S_col[blk * D + d] = pro_tf[blk * D + d] * (0.5f + g);
}

// ---------------- kernel 4: mean pools -> x (B x 128) ----------------
// grid: B blocks, 64 threads
__global__ void k_pool(const float* __restrict__ smi_tfs,
                       const float* __restrict__ pro_tfs,
                       float* __restrict__ x)
{
    int b = blockIdx.x, d = threadIdx.x;
    float s = 0.f;
    for (int i = 0; i < ND; ++i) s += smi_tfs[(b * ND + i) * D + d];
    x[b * 128 + d] = s * (1.0f / ND);
    float p = 0.f;
    for (int j = 0; j < NP; ++j) p += pro_tfs[(b * NP + j) * D + d];
    x[b * 128 + 64 + d] = p * (1.0f / NP);
}

// ---------------- MLP ----------------
// L1: h1[b][o] = relu(x[b,:128] @ w1[:,o] + b1[o]);  8192 threads
__global__ void k_lin1(const float* __restrict__ x, const float* __restrict__ w1,
                       const float* __restrict__ b1, float* __restrict__ h1)
{
    int tid = blockIdx.x * 256 + threadIdx.x;
    int o = tid & 1023, b = tid >> 10;
    float acc = b1[o];
    const float* xr = x + b * 128;
    #pragma unroll 4
    for (int k = 0; k < 128; ++k) acc = fmaf(xr[k], w1[k * 1024 + o], acc);
    h1[tid] = fmaxf(acc, 0.f);
}

// L2 split over 8 k-chunks of 128: partial dots.  65536 threads
__global__ void k_lin2_part(const float* __restrict__ h1, const float* __restrict__ w2,
                            float* __restrict__ part)
{
    int tid = blockIdx.x * 256 + threadIdx.x;
    int o = tid & 1023;
    int kc = (tid >> 10) & 7;
    int b = tid >> 13;
    float acc = 0.f;
    const float* hr = h1 + b * 1024 + kc * 128;
    const float* wr = w2 + (size_t)(kc * 128) * 1024 + o;
    #pragma unroll 4
    for (int k = 0; k < 128; ++k) acc = fmaf(hr[k], wr[(size_t)k * 1024], acc);
    part[tid] = acc;
}
__global__ void k_lin2_fin(const float* __restrict__ part, const float* __restrict__ b2,
                           float* __restrict__ h2)
{
    int tid = blockIdx.x * 256 + threadIdx.x;  // 8192
    int o = tid & 1023, b = tid >> 10;
    float s = b2[o];
    #pragma unroll
    for (int kc = 0; kc < 8; ++kc) s += part[((b * 8 + kc) << 10) + o];
    h2[tid] = fmaxf(s, 0.f);
}

// L3: O=512, K=1024 split over 8 chunks.  32768 threads
__global__ void k_lin3_part(const float* __restrict__ h2, const float* __restrict__ w3,
                            float* __restrict__ part)
{
    int tid = blockIdx.x * 256 + threadIdx.x;
    int o = tid & 511;
    int kc = (tid >> 9) & 7;
    int b = tid >> 12;
    float acc = 0.f;
    const float* hr = h2 + b * 1024 + kc * 128;
    const float* wr = w3 + (size_t)(kc * 128) * 512 + o;
    #pragma unroll 4
    for (int k = 0; k < 128; ++k) acc = fmaf(hr[k], wr[(size_t)k * 512], acc);
    part[tid] = acc;
}
__global__ void k_lin3_fin(const float* __restrict__ part, const float* __restrict__ b3,
                           float* __restrict__ h3)
{
    int tid = blockIdx.x * 256 + threadIdx.x;  // 4096
    int o = tid & 511, b = tid >> 9;
    float s = b3[o];
    #pragma unroll
    for (int kc = 0; kc < 8; ++kc) s += part[((b * 8 + kc) << 9) + o];
    h3[tid] = fmaxf(s, 0.f);
}

// L4: out[b][o] = h3[b,:512] @ w4[:,o] + b4[o];  one wave per (b,o)
__global__ void k_lin4(const float* __restrict__ h3, const float* __restrict__ w4,
                       const float* __restrict__ b4, float* __restrict__ out)
{
    int t = threadIdx.x;
    int w = t >> 6;          // 0..15
    int lane = t & 63;
    int b = w >> 1, o = w & 1;
    float acc = 0.f;
    for (int k = lane; k < 512; k += 64)
        acc += h3[b * 512 + k] * w4[k * 2 + o];
    for (int off = 32; off > 0; off >>= 1)
        acc += __shfl_down(acc, off, 64);
    if (lane == 0) out[b * 2 + o] = acc + b4[o];
}

extern "C" void kernel_launch(void* const* d_in, const int* in_sizes, int n_in,
                              void* d_out, int out_size, void* d_ws, size_t ws_size,
                              hipStream_t stream)
{
    const float* smi_tf   = (const float*)d_in[0];
    const float* pro_tf   = (const float*)d_in[1];
    const float* drug_gat = (const float*)d_in[2];
    const float* w_att    = (const float*)d_in[3];
    const float* b_att    = (const float*)d_in[4];
    const float* w1 = (const float*)d_in[5];
    const float* b1 = (const float*)d_in[6];
    const float* w2 = (const float*)d_in[7];
    const float* b2 = (const float*)d_in[8];
    const float* w3 = (const float*)d_in[9];
    const float* b3 = (const float*)d_in[10];
    const float* w4 = (const float*)d_in[11];
    const float* b4 = (const float*)d_in[12];
    float* out = (float*)d_out;

    float* ws = (float*)d_ws;
    float* smi_attss = ws;                  // B*ND*D   = 74240
    float* pro_att   = smi_attss + 74240;   // B*NP*D   = 512000
    float* S_row     = pro_att + 512000;    // 74240  (later smi_tfs)
    float* S_col     = S_row + 74240;       // 512000 (later pro_tfs)
    float* x   = S_col + 512000;            // 1024
    float* h1  = x + 1024;                  // 8192
    float* h2  = h1 + 8192;                 // 8192
    float* h3  = h2 + 8192;                 // 4096
    float* p2  = h3 + 4096;                 // 65536
    float* p3  = p2 + 65536;                // 32768

    k_proj    <<<B * (NSMI + NP + NATOM), 64, 0, stream>>>(smi_tf, pro_tf, drug_gat,
                                                           w_att, b_att, smi_attss, pro_att);
    k_rowsum  <<<B * ND, 256, 0, stream>>>(smi_attss, pro_att, S_row);
    k_colsum  <<<B * NP, 256, 0, stream>>>(smi_attss, pro_att, S_col);
    k_gate_smi<<<B * ND, 64, 0, stream>>>(smi_attss, w_att, b_att, S_row);
    k_gate_pro<<<B * NP, 64, 0, stream>>>(pro_tf, w_att, b_att, S_col);
    k_pool    <<<B, 64, 0, stream>>>(S_row, S_col, x);
    k_lin1    <<<32, 256, 0, stream>>>(x, w1, b1, h1);
    k_lin2_part<<<256, 256, 0, stream>>>(h1, w2, p2);
    k_lin2_fin<<<32, 256, 0, stream>>>(p2, b2, h2);
    k_lin3_part<<<128, 256, 0, stream>>>(h2, w3, p3);
    k_lin3_fin<<<16, 256, 0, stream>>>(p3, b3, h3);
    k_lin4    <<<1, 1024, 0, stream>>>(h3, w4, b4, out);
}

// Round 2
// 166.270 us; speedup vs baseline: 1.7439x; 1.7439x over previous
//
#include <hip/hip_runtime.h>
#include <math.h>

#define B 8
#define NSMI 100
#define NATOM 45
#define ND 145      // NSMI + NATOM
#define NP 1000
#define D 64

__device__ __forceinline__ float4 f4zero() { float4 z; z.x=z.y=z.z=z.w=0.f; return z; }

// ---------------- kernel 1: shared attention projection ----------------
// grid: B*(NSMI+NP+NATOM) blocks, 64 threads.
__global__ void k_proj(const float* __restrict__ smi_tf,
                       const float* __restrict__ pro_tf,
                       const float* __restrict__ drug_gat,
                       const float* __restrict__ w_att,
                       const float* __restrict__ b_att,
                       float* __restrict__ smi_attss,
                       float* __restrict__ pro_att)
{
    __shared__ float row[D];
    int blk = blockIdx.x;
    int b = blk / (NSMI + NP + NATOM);
    int rr = blk - b * (NSMI + NP + NATOM);
    int d = threadIdx.x;
    if (rr < NSMI) {
        row[d] = smi_tf[(b * NSMI + rr) * D + d];
        __syncthreads();
        float acc = b_att[d];
        #pragma unroll
        for (int k = 0; k < D; ++k) acc = fmaf(row[k], w_att[k * D + d], acc);
        smi_attss[(b * ND + rr) * D + d] = acc;
    } else if (rr < NSMI + NP) {
        int j = rr - NSMI;
        row[d] = pro_tf[(b * NP + j) * D + d];
        __syncthreads();
        float acc = b_att[d];
        #pragma unroll
        for (int k = 0; k < D; ++k) acc = fmaf(row[k], w_att[k * D + d], acc);
        pro_att[(b * NP + j) * D + d] = acc;
    } else {
        int a = rr - NSMI - NP;
        smi_attss[(b * ND + NSMI + a) * D + d] = drug_gat[(b * NATOM + a) * D + d];
    }
}

// ---------------- kernel 2a: rowsum + smi gate fused ----------------
// grid: B * 73 blocks (2 i's per block), 256 threads = 4 waves.
// wave w: i = i0 + (w&1), j-slice s = (w>>1)*4 + (lane>>4)  (8 slices)
// lane&15 = d-group (float4). Then gate: smi_tfs = smi_attss*(0.5+sigmoid((S/NP)@w_att+b_att))
__global__ __launch_bounds__(256) void k_rowsum2(
    const float4* __restrict__ smi4, const float4* __restrict__ pro4,
    const float* __restrict__ smi_attss,
    const float* __restrict__ w_att, const float* __restrict__ b_att,
    float* __restrict__ smi_tfs)
{
    int blk = blockIdx.x;
    int b = blk / 73;
    int i0 = (blk - b * 73) * 2;
    int t = threadIdx.x;
    int w = t >> 6;
    int lane = t & 63;
    int l = lane & 15;
    int g = lane >> 4;
    int io = w & 1;
    int s = ((w >> 1) << 2) + g;       // 0..7
    int i = i0 + io;
    bool valid = (i < ND);

    float4 a = valid ? smi4[(size_t)(b * ND + i) * 16 + l] : f4zero();
    const float4* p = pro4 + (size_t)b * NP * 16 + s * 16 + l;
    float4 acc = f4zero();
    #pragma unroll 5
    for (int it = 0; it < 125; ++it) {     // j = s + 8*it
        float4 pv = p[it * 128];
        acc.x += fmaxf(0.f, a.x + pv.x);
        acc.y += fmaxf(0.f, a.y + pv.y);
        acc.z += fmaxf(0.f, a.z + pv.z);
        acc.w += fmaxf(0.f, a.w + pv.w);
    }
    // reduce over g (lane bits 4,5)
    acc.x += __shfl_xor(acc.x, 16, 64); acc.x += __shfl_xor(acc.x, 32, 64);
    acc.y += __shfl_xor(acc.y, 16, 64); acc.y += __shfl_xor(acc.y, 32, 64);
    acc.z += __shfl_xor(acc.z, 16, 64); acc.z += __shfl_xor(acc.z, 32, 64);
    acc.w += __shfl_xor(acc.w, 16, 64); acc.w += __shfl_xor(acc.w, 32, 64);

    __shared__ float4 red[4][16];
    __shared__ float vlds[2][64];
    if (lane < 16) red[w][l] = acc;
    __syncthreads();
    if (t < 32) {
        int io2 = t >> 4, l2 = t & 15;
        float4 s4;
        s4.x = red[io2][l2].x + red[io2 + 2][l2].x;
        s4.y = red[io2][l2].y + red[io2 + 2][l2].y;
        s4.z = red[io2][l2].z + red[io2 + 2][l2].z;
        s4.w = red[io2][l2].w + red[io2 + 2][l2].w;
        vlds[io2][l2 * 4 + 0] = s4.x * (1.0f / NP);
        vlds[io2][l2 * 4 + 1] = s4.y * (1.0f / NP);
        vlds[io2][l2 * 4 + 2] = s4.z * (1.0f / NP);
        vlds[io2][l2 * 4 + 3] = s4.w * (1.0f / NP);
    }
    __syncthreads();
    if (t < 128) {
        int io2 = t >> 6, d = t & 63;
        int ii = i0 + io2;
        if (ii < ND) {
            float m = b_att[d];
            #pragma unroll
            for (int k = 0; k < D; ++k) m = fmaf(vlds[io2][k], w_att[k * D + d], m);
            float gs = 1.f / (1.f + expf(-m));
            size_t idx = (size_t)(b * ND + ii) * D + d;
            smi_tfs[idx] = smi_attss[idx] * (0.5f + gs);
        }
    }
}

// ---------------- kernel 2b: colsum + pro gate fused ----------------
// grid: B * 125 blocks (8 j's per block, one j per wave), 512 threads.
__global__ __launch_bounds__(512) void k_colsum2(
    const float4* __restrict__ smi4, const float4* __restrict__ pro4,
    const float* __restrict__ pro_tf,
    const float* __restrict__ w_att, const float* __restrict__ b_att,
    float* __restrict__ pro_tfs)
{
    int blk = blockIdx.x;
    int b = blk / 125;
    int j = (blk - b * 125) * 8 + (threadIdx.x >> 6);
    int w = threadIdx.x >> 6;
    int lane = threadIdx.x & 63;
    int l = lane & 15;
    int g = lane >> 4;

    float4 p = pro4[(size_t)(b * NP + j) * 16 + l];
    const float4* ab = smi4 + (size_t)b * ND * 16 + g * 16 + l;
    float4 acc = f4zero();
    #pragma unroll 6
    for (int it = 0; it < 36; ++it) {      // i = g + 4*it  (<=143)
        float4 av = ab[it * 64];
        acc.x += fmaxf(0.f, av.x + p.x);
        acc.y += fmaxf(0.f, av.y + p.y);
        acc.z += fmaxf(0.f, av.z + p.z);
        acc.w += fmaxf(0.f, av.w + p.w);
    }
    if (g == 0) {                          // i = 144
        float4 av = ab[36 * 64];
        acc.x += fmaxf(0.f, av.x + p.x);
        acc.y += fmaxf(0.f, av.y + p.y);
        acc.z += fmaxf(0.f, av.z + p.z);
        acc.w += fmaxf(0.f, av.w + p.w);
    }
    acc.x += __shfl_xor(acc.x, 16, 64); acc.x += __shfl_xor(acc.x, 32, 64);
    acc.y += __shfl_xor(acc.y, 16, 64); acc.y += __shfl_xor(acc.y, 32, 64);
    acc.z += __shfl_xor(acc.z, 16, 64); acc.z += __shfl_xor(acc.z, 32, 64);
    acc.w += __shfl_xor(acc.w, 16, 64); acc.w += __shfl_xor(acc.w, 32, 64);

    __shared__ float vlds[8][64];
    if (lane < 16) {
        vlds[w][l * 4 + 0] = acc.x * (1.0f / ND);
        vlds[w][l * 4 + 1] = acc.y * (1.0f / ND);
        vlds[w][l * 4 + 2] = acc.z * (1.0f / ND);
        vlds[w][l * 4 + 3] = acc.w * (1.0f / ND);
    }
    __syncthreads();
    int d = lane;
    float m = b_att[d];
    #pragma unroll
    for (int k = 0; k < D; ++k) m = fmaf(vlds[w][k], w_att[k * D + d], m);
    float gs = 1.f / (1.f + expf(-m));
    size_t idx = (size_t)(b * NP + j) * D + d;
    pro_tfs[idx] = pro_tf[idx] * (0.5f + gs);
}

// ---------------- kernel 3: mean pools -> x (B x 128) ----------------
// grid: B blocks, 256 threads, float4
__global__ void k_pool2(const float4* __restrict__ smi_tfs4,
                        const float4* __restrict__ pro_tfs4,
                        float* __restrict__ x)
{
    int b = blockIdx.x;
    int t = threadIdx.x;
    int l = t & 15, c = t >> 4;
    float4 s = f4zero(), p = f4zero();
    for (int i = c; i < ND; i += 16) {
        float4 v = smi_tfs4[(size_t)(b * ND + i) * 16 + l];
        s.x += v.x; s.y += v.y; s.z += v.z; s.w += v.w;
    }
    for (int jj = c; jj < NP; jj += 16) {
        float4 v = pro_tfs4[(size_t)(b * NP + jj) * 16 + l];
        p.x += v.x; p.y += v.y; p.z += v.z; p.w += v.w;
    }
    __shared__ float4 rs[256], rp[256];
    rs[t] = s; rp[t] = p;
    __syncthreads();
    if (t < 16) {
        float4 S = rs[t], P = rp[t];
        for (int c2 = 1; c2 < 16; ++c2) {
            float4 a = rs[c2 * 16 + t], q = rp[c2 * 16 + t];
            S.x += a.x; S.y += a.y; S.z += a.z; S.w += a.w;
            P.x += q.x; P.y += q.y; P.z += q.z; P.w += q.w;
        }
        x[b * 128 + t * 4 + 0] = S.x * (1.0f / ND);
        x[b * 128 + t * 4 + 1] = S.y * (1.0f / ND);
        x[b * 128 + t * 4 + 2] = S.z * (1.0f / ND);
        x[b * 128 + t * 4 + 3] = S.w * (1.0f / ND);
        x[b * 128 + 64 + t * 4 + 0] = P.x * (1.0f / NP);
        x[b * 128 + 64 + t * 4 + 1] = P.y * (1.0f / NP);
        x[b * 128 + 64 + t * 4 + 2] = P.z * (1.0f / NP);
        x[b * 128 + 64 + t * 4 + 3] = P.w * (1.0f / NP);
    }
}

// ---------------- MLP ----------------
// L1: 8192 threads, each 128 fmas
__global__ void k_lin1(const float* __restrict__ x, const float* __restrict__ w1,
                       const float* __restrict__ b1, float* __restrict__ h1)
{
    int tid = blockIdx.x * 256 + threadIdx.x;
    int o = tid & 1023, b = tid >> 10;
    float acc = b1[o];
    const float* xr = x + b * 128;
    #pragma unroll 8
    for (int k = 0; k < 128; ++k) acc = fmaf(xr[k], w1[k * 1024 + o], acc);
    h1[tid] = fmaxf(acc, 0.f);
}

// L2 fused: grid 8*16 blocks, 512 threads; block = (b, 64 outputs), 8 k-chunks of 128
__global__ __launch_bounds__(512) void k_lin2f(
    const float* __restrict__ h1, const float* __restrict__ w2,
    const float* __restrict__ b2, float* __restrict__ h2)
{
    int b = blockIdx.x >> 4, och = blockIdx.x & 15;
    int t = threadIdx.x;
    int ol = t & 63, kc = t >> 6;
    int o = och * 64 + ol;
    __shared__ float hs[1024];
    hs[t] = h1[b * 1024 + t];
    hs[t + 512] = h1[b * 1024 + 512 + t];
    __syncthreads();
    float acc = 0.f;
    const float* wp = w2 + (size_t)(kc * 128) * 1024 + o;
    const float* hp = hs + kc * 128;
    #pragma unroll 8
    for (int k = 0; k < 128; ++k) acc = fmaf(hp[k], wp[(size_t)k * 1024], acc);
    __shared__ float red[512];
    red[t] = acc;
    __syncthreads();
    if (t < 64) {
        float sAcc = b2[och * 64 + t];
        #pragma unroll
        for (int c = 0; c < 8; ++c) sAcc += red[c * 64 + t];
        h2[b * 1024 + och * 64 + t] = fmaxf(sAcc, 0.f);
    }
}

// L3 fused: grid 8*8 blocks, 512 threads; block = (b, 64 outputs of 512), 8 k-chunks of 128
__global__ __launch_bounds__(512) void k_lin3f(
    const float* __restrict__ h2, const float* __restrict__ w3,
    const float* __restrict__ b3, float* __restrict__ h3)
{
    int b = blockIdx.x >> 3, och = blockIdx.x & 7;
    int t = threadIdx.x;
    int ol = t & 63, kc = t >> 6;
    int o = och * 64 + ol;
    __shared__ float hs[1024];
    hs[t] = h2[b * 1024 + t];
    hs[t + 512] = h2[b * 1024 + 512 + t];
    __syncthreads();
    float acc = 0.f;
    const float* wp = w3 + (size_t)(kc * 128) * 512 + o;
    const float* hp = hs + kc * 128;
    #pragma unroll 8
    for (int k = 0; k < 128; ++k) acc = fmaf(hp[k], wp[(size_t)k * 512], acc);
    __shared__ float red[512];
    red[t] = acc;
    __syncthreads();
    if (t < 64) {
        float sAcc = b3[och * 64 + t];
        #pragma unroll
        for (int c = 0; c < 8; ++c) sAcc += red[c * 64 + t];
        h3[b * 512 + och * 64 + t] = fmaxf(sAcc, 0.f);
    }
}

// L4: out[b][o], one wave per (b,o)
__global__ void k_lin4(const float* __restrict__ h3, const float* __restrict__ w4,
                       const float* __restrict__ b4, float* __restrict__ out)
{
    int t = threadIdx.x;
    int w = t >> 6;
    int lane = t & 63;
    int b = w >> 1, o = w & 1;
    float acc = 0.f;
    for (int k = lane; k < 512; k += 64)
        acc += h3[b * 512 + k] * w4[k * 2 + o];
    for (int off = 32; off > 0; off >>= 1)
        acc += __shfl_down(acc, off, 64);
    if (lane == 0) out[b * 2 + o] = acc + b4[o];
}

extern "C" void kernel_launch(void* const* d_in, const int* in_sizes, int n_in,
                              void* d_out, int out_size, void* d_ws, size_t ws_size,
                              hipStream_t stream)
{
    const float* smi_tf   = (const float*)d_in[0];
    const float* pro_tf   = (const float*)d_in[1];
    const float* drug_gat = (const float*)d_in[2];
    const float* w_att    = (const float*)d_in[3];
    const float* b_att    = (const float*)d_in[4];
    const float* w1 = (const float*)d_in[5];
    const float* b1 = (const float*)d_in[6];
    const float* w2 = (const float*)d_in[7];
    const float* b2 = (const float*)d_in[8];
    const float* w3 = (const float*)d_in[9];
    const float* b3 = (const float*)d_in[10];
    const float* w4 = (const float*)d_in[11];
    const float* b4 = (const float*)d_in[12];
    float* out = (float*)d_out;

    float* ws = (float*)d_ws;
    float* smi_attss = ws;                   // 74240
    float* pro_att   = smi_attss + 74240;    // 512000
    float* smi_tfs   = pro_att + 512000;     // 74240
    float* pro_tfs   = smi_tfs + 74240;      // 512000
    float* x   = pro_tfs + 512000;           // 1024
    float* h1  = x + 1024;                   // 8192
    float* h2  = h1 + 8192;                  // 8192
    float* h3  = h2 + 8192;                  // 4096

    k_proj   <<<B * (NSMI + NP + NATOM), 64, 0, stream>>>(smi_tf, pro_tf, drug_gat,
                                                          w_att, b_att, smi_attss, pro_att);
    k_rowsum2<<<B * 73, 256, 0, stream>>>((const float4*)smi_attss, (const float4*)pro_att,
                                          smi_attss, w_att, b_att, smi_tfs);
    k_colsum2<<<B * 125, 512, 0, stream>>>((const float4*)smi_attss, (const float4*)pro_att,
                                           pro_tf, w_att, b_att, pro_tfs);
    k_pool2  <<<B, 256, 0, stream>>>((const float4*)smi_tfs, (const float4*)pro_tfs, x);
    k_lin1   <<<32, 256, 0, stream>>>(x, w1, b1, h1);
    k_lin2f  <<<128, 512, 0, stream>>>(h1, w2, b2, h2);
    k_lin3f  <<<64, 512, 0, stream>>>(h2, w3, b3, h3);
    k_lin4   <<<1, 1024, 0, stream>>>(h3, w4, b4, out);
}

// Round 7
// 157.094 us; speedup vs baseline: 1.8458x; 1.0584x over previous
//
#include <hip/hip_runtime.h>
#include <math.h>

#define B 8
#define NSMI 100
#define NATOM 45
#define ND 145      // NSMI + NATOM
#define NP 1000
#define D 64
#define NROW 1145   // ND + NP rows per batch

#define PROJ_RPB 16
#define PROJ_BPB 72          // ceil(1145/16)
#define ROW_BPB 37           // ceil(145/4)   rowsum blocks per batch (4 i's each)
#define COL_BPB 250          // 1000/4        colsum blocks per batch (4 j's each)
#define PAIR_ROW_BLKS (B * ROW_BPB)            // 296
#define PAIR_BLKS (PAIR_ROW_BLKS + B * COL_BPB) // 2296
#define TAIL_BLKS 128

__device__ __forceinline__ float4 f4z() { float4 z; z.x = z.y = z.z = z.w = 0.f; return z; }
__device__ __forceinline__ void f4acc(float4& a, const float4& v) {
    a.x += v.x; a.y += v.y; a.z += v.z; a.w += v.w;
}
__device__ __forceinline__ void acc_relu(float4& acc, const float4& a, const float4& p) {
    acc.x += fmaxf(0.f, a.x + p.x);
    acc.y += fmaxf(0.f, a.y + p.y);
    acc.z += fmaxf(0.f, a.z + p.z);
    acc.w += fmaxf(0.f, a.w + p.w);
}
__device__ __forceinline__ void wave_red_g(float4& v) {
    v.x += __shfl_xor(v.x, 16, 64); v.x += __shfl_xor(v.x, 32, 64);
    v.y += __shfl_xor(v.y, 16, 64); v.y += __shfl_xor(v.y, 32, 64);
    v.z += __shfl_xor(v.z, 16, 64); v.z += __shfl_xor(v.z, 32, 64);
    v.w += __shfl_xor(v.w, 16, 64); v.w += __shfl_xor(v.w, 32, 64);
}

// device-scope grid barrier (all TAIL_BLKS blocks co-resident: 128 blocks <= 256 CUs)
__device__ __forceinline__ void gridbar(int* bar, int ph, int nblk) {
    __syncthreads();
    if (threadIdx.x == 0) {
        __threadfence();
        __hip_atomic_fetch_add(&bar[ph], 1, __ATOMIC_ACQ_REL, __HIP_MEMORY_SCOPE_AGENT);
        while (__hip_atomic_load(&bar[ph], __ATOMIC_ACQUIRE, __HIP_MEMORY_SCOPE_AGENT) < nblk)
            __builtin_amdgcn_s_sleep(1);
        __threadfence();
    }
    __syncthreads();
}

// ============ K1: projection (smi, pro) + drug_gat copy; zero barrier slots ============
// grid: B*72 blocks, 256 threads. 16 rows/block, w_att staged in LDS once per block.
__global__ __launch_bounds__(256) void k_proj2(
    const float* __restrict__ smi_tf, const float* __restrict__ pro_tf,
    const float* __restrict__ drug_gat, const float* __restrict__ w_att,
    const float* __restrict__ b_att,
    float* __restrict__ smi_attss, float* __restrict__ pro_att, int* __restrict__ bar)
{
    int blk = blockIdx.x, t = threadIdx.x;
    if (blk == 0 && t < 16) bar[t] = 0;
    int b = blk / PROJ_BPB;
    int r0 = (blk - b * PROJ_BPB) * PROJ_RPB;

    __shared__ float4 wl[64 * 17];   // [k][16 d4-slots + pad]
    __shared__ float4 rl4[16 * 17];  // [row][16 + pad]

    #pragma unroll
    for (int i2 = 0; i2 < 4; ++i2) {
        int f = t + 256 * i2;              // float4 index into w_att (1024 total)
        float4 v = ((const float4*)w_att)[f];
        wl[(f >> 4) * 17 + (f & 15)] = v;
    }
    int rl = t >> 4, p = t & 15;
    int r = r0 + rl;
    {
        float4 v = f4z();
        if (r < NROW) {
            const float* src;
            if (r < NSMI)      src = smi_tf   + (size_t)(b * NSMI + r) * D;
            else if (r < ND)   src = drug_gat + (size_t)(b * NATOM + (r - NSMI)) * D;
            else               src = pro_tf   + (size_t)(b * NP + (r - ND)) * D;
            v = ((const float4*)src)[p];
        }
        rl4[rl * 17 + p] = v;
    }
    __syncthreads();
    if (r >= NROW) return;
    float4 out;
    if (r >= NSMI && r < ND) {
        out = rl4[rl * 17 + p];            // drug_gat copy path
    } else {
        float4 acc = ((const float4*)b_att)[p];
        const float* rowf = (const float*)rl4;
        #pragma unroll
        for (int k = 0; k < 64; ++k) {
            float val = rowf[rl * 68 + k];
            float4 w = wl[k * 17 + p];
            acc.x = fmaf(val, w.x, acc.x);
            acc.y = fmaf(val, w.y, acc.y);
            acc.z = fmaf(val, w.z, acc.z);
            acc.w = fmaf(val, w.w, acc.w);
        }
        out = acc;
    }
    if (r < ND) ((float4*)smi_attss)[(size_t)(b * ND + r) * 16 + p] = out;
    else        ((float4*)pro_att)[(size_t)(b * NP + (r - ND)) * 16 + p] = out;
}

// ============ K2: fused pair-sums + gates, role-split blocks ============
// blocks [0, 296): rowsum role, 4 i's per block; blocks [296, 2296): colsum role, 4 j's per block.
// 512 threads: wave w (0..7), lane: l = lane&15 (d4), g = lane>>4; u = w*4+g (0..31) = panel slice.
__global__ __launch_bounds__(512) void k_pair(
    const float4* __restrict__ smi4, const float4* __restrict__ pro4,
    const float* __restrict__ smi_attss, const float* __restrict__ pro_tf,
    const float* __restrict__ w_att, const float* __restrict__ b_att,
    float* __restrict__ smi_tfs, float* __restrict__ pro_tfs)
{
    __shared__ float4 red[8][4][16];
    __shared__ float vl[4][64];
    int blk = blockIdx.x, t = threadIdx.x;
    int w = t >> 6, lane = t & 63, l = lane & 15, g = lane >> 4;
    int u = w * 4 + g;                       // 0..31
    float4 acc0 = f4z(), acc1 = f4z(), acc2 = f4z(), acc3 = f4z();
    int b, base;
    bool isRow = (blk < PAIR_ROW_BLKS);

    if (isRow) {
        b = blk / ROW_BPB;
        base = (blk - b * ROW_BPB) * 4;      // i0
        float4 a0 = (base + 0 < ND) ? smi4[(size_t)(b * ND + base + 0) * 16 + l] : f4z();
        float4 a1 = (base + 1 < ND) ? smi4[(size_t)(b * ND + base + 1) * 16 + l] : f4z();
        float4 a2 = (base + 2 < ND) ? smi4[(size_t)(b * ND + base + 2) * 16 + l] : f4z();
        float4 a3 = (base + 3 < ND) ? smi4[(size_t)(b * ND + base + 3) * 16 + l] : f4z();
        const float4* pp = pro4 + (size_t)b * NP * 16 + u * 16 + l;   // j = u + 32*it
        #pragma unroll 4
        for (int it = 0; it < 31; ++it) {
            float4 pv = pp[it * 512];
            acc_relu(acc0, a0, pv); acc_relu(acc1, a1, pv);
            acc_relu(acc2, a2, pv); acc_relu(acc3, a3, pv);
        }
        if (u < 8) {                          // j = u + 992 < 1000
            float4 pv = pp[31 * 512];
            acc_relu(acc0, a0, pv); acc_relu(acc1, a1, pv);
            acc_relu(acc2, a2, pv); acc_relu(acc3, a3, pv);
        }
    } else {
        int cb = blk - PAIR_ROW_BLKS;
        b = cb / COL_BPB;
        base = (cb - b * COL_BPB) * 4;       // j0
        float4 p0 = pro4[(size_t)(b * NP + base + 0) * 16 + l];
        float4 p1 = pro4[(size_t)(b * NP + base + 1) * 16 + l];
        float4 p2 = pro4[(size_t)(b * NP + base + 2) * 16 + l];
        float4 p3 = pro4[(size_t)(b * NP + base + 3) * 16 + l];
        const float4* ap = smi4 + (size_t)b * ND * 16 + u * 16 + l;   // i = u + 32*it
        #pragma unroll
        for (int it = 0; it < 4; ++it) {
            float4 av = ap[it * 512];
            acc_relu(acc0, av, p0); acc_relu(acc1, av, p1);
            acc_relu(acc2, av, p2); acc_relu(acc3, av, p3);
        }
        if (u < 17) {                         // i = u + 128 < 145
            float4 av = ap[4 * 512];
            acc_relu(acc0, av, p0); acc_relu(acc1, av, p1);
            acc_relu(acc2, av, p2); acc_relu(acc3, av, p3);
        }
    }

    wave_red_g(acc0); wave_red_g(acc1); wave_red_g(acc2); wave_red_g(acc3);
    if (lane < 16) {
        red[w][0][l] = acc0; red[w][1][l] = acc1;
        red[w][2][l] = acc2; red[w][3][l] = acc3;
    }
    __syncthreads();
    float invn = isRow ? (1.0f / NP) : (1.0f / ND);
    if (t < 64) {
        int ii = t >> 4, l2 = t & 15;
        float4 s = f4z();
        #pragma unroll
        for (int w2 = 0; w2 < 8; ++w2) f4acc(s, red[w2][ii][l2]);
        vl[ii][l2 * 4 + 0] = s.x * invn;
        vl[ii][l2 * 4 + 1] = s.y * invn;
        vl[ii][l2 * 4 + 2] = s.z * invn;
        vl[ii][l2 * 4 + 3] = s.w * invn;
    }
    __syncthreads();
    if (t < 256) {
        int ii = t >> 6, d = t & 63;
        int r = base + ii;
        bool ok = isRow ? (r < ND) : true;
        if (ok) {
            float m = b_att[d];
            #pragma unroll
            for (int k = 0; k < 64; ++k) m = fmaf(vl[ii][k], w_att[k * 64 + d], m);
            float gs = 1.f / (1.f + expf(-m));
            if (isRow) {
                size_t idx = (size_t)(b * ND + r) * 64 + d;
                smi_tfs[idx] = smi_attss[idx] * (0.5f + gs);
            } else {
                size_t idx = (size_t)(b * NP + r) * 64 + d;
                pro_tfs[idx] = pro_tf[idx] * (0.5f + gs);
            }
        }
    }
}

// ============ K3: pool + 4-layer MLP, single kernel with software grid barriers ============
// 128 blocks x 512 threads, all co-resident.
__global__ __launch_bounds__(512) void k_tail(
    const float4* __restrict__ smi_tfs4, const float4* __restrict__ pro_tfs4,
    const float* __restrict__ w1, const float* __restrict__ b1,
    const float* __restrict__ w2, const float* __restrict__ b2,
    const float* __restrict__ w3, const float* __restrict__ b3,
    const float* __restrict__ w4p, const float* __restrict__ b4p,
    float* __restrict__ x, float* __restrict__ h1, float* __restrict__ h2,
    float* __restrict__ h3, int* __restrict__ bar, float* __restrict__ out)
{
    __shared__ float4 ldsb[1024];            // 16 KB, reused per phase
    float* lds = (float*)ldsb;
    int blk = blockIdx.x, t = threadIdx.x;

    // ---- P0: mean pools -> x[B][128].  block (b, s): d4-slice s of batch b
    {
        int b = blk >> 4, s = blk & 15;
        float4 sa = f4z(), pa = f4z();
        if (t < ND) f4acc(sa, smi_tfs4[(size_t)(b * ND + t) * 16 + s]);
        for (int j = t; j < NP; j += 512) f4acc(pa, pro_tfs4[(size_t)(b * NP + j) * 16 + s]);
        ldsb[t] = sa; ldsb[512 + t] = pa;
        __syncthreads();
        for (int st = 256; st > 0; st >>= 1) {
            if (t < st) { f4acc(ldsb[t], ldsb[t + st]); f4acc(ldsb[512 + t], ldsb[512 + t + st]); }
            __syncthreads();
        }
        if (t == 0) {
            float4 S = ldsb[0], P = ldsb[512];
            x[b * 128 + s * 4 + 0] = S.x * (1.0f / ND);
            x[b * 128 + s * 4 + 1] = S.y * (1.0f / ND);
            x[b * 128 + s * 4 + 2] = S.z * (1.0f / ND);
            x[b * 128 + s * 4 + 3] = S.w * (1.0f / ND);
            x[b * 128 + 64 + s * 4 + 0] = P.x * (1.0f / NP);
            x[b * 128 + 64 + s * 4 + 1] = P.y * (1.0f / NP);
            x[b * 128 + 64 + s * 4 + 2] = P.z * (1.0f / NP);
            x[b * 128 + 64 + s * 4 + 3] = P.w * (1.0f / NP);
        }
    }
    gridbar(bar, 0, TAIL_BLKS);

    // ---- P1: h1 = relu(x @ w1 + b1).  block (b, och): 64 outputs, kc = t>>6 over k-range 16
    {
        int b = blk >> 4, och = blk & 15;
        int ol = t & 63, kc = t >> 6;
        int o = och * 64 + ol;
        const float* xr = x + b * 128 + kc * 16;
        const float* wp = w1 + (size_t)(kc * 16) * 1024 + o;
        float acc = 0.f;
        #pragma unroll
        for (int k = 0; k < 16; ++k) acc = fmaf(xr[k], wp[(size_t)k * 1024], acc);
        lds[t] = acc;
        __syncthreads();
        if (t < 64) {
            float v = b1[och * 64 + t];
            #pragma unroll
            for (int c = 0; c < 8; ++c) v += lds[c * 64 + t];
            h1[b * 1024 + och * 64 + t] = fmaxf(v, 0.f);
        }
    }
    gridbar(bar, 1, TAIL_BLKS);

    // ---- P2: h2 = relu(h1 @ w2 + b2).  block (b, och): 64 outputs, kc over k-range 128
    {
        int b = blk >> 4, och = blk & 15;
        int ol = t & 63, kc = t >> 6;
        int o = och * 64 + ol;
        const float* hp = h1 + b * 1024 + kc * 128;
        const float* wp = w2 + (size_t)(kc * 128) * 1024 + o;
        float acc = 0.f;
        #pragma unroll 8
        for (int k = 0; k < 128; ++k) acc = fmaf(hp[k], wp[(size_t)k * 1024], acc);
        __syncthreads();
        lds[t] = acc;
        __syncthreads();
        if (t < 64) {
            float v = b2[och * 64 + t];
            #pragma unroll
            for (int c = 0; c < 8; ++c) v += lds[c * 64 + t];
            h2[b * 1024 + och * 64 + t] = fmaxf(v, 0.f);
        }
    }
    gridbar(bar, 2, TAIL_BLKS);

    // ---- P3: h3 = relu(h2 @ w3 + b3).  block (b, och): 32 outputs, kc = t>>5 over k-range 64
    {
        int b = blk >> 4, och = blk & 15;
        int ol = t & 31, kc = t >> 5;
        int o = och * 32 + ol;
        const float* hp = h2 + b * 1024 + kc * 64;
        const float* wp = w3 + (size_t)(kc * 64) * 512 + o;
        float acc = 0.f;
        #pragma unroll 8
        for (int k = 0; k < 64; ++k) acc = fmaf(hp[k], wp[(size_t)k * 512], acc);
        __syncthreads();
        lds[t] = acc;
        __syncthreads();
        if (t < 32) {
            float v = b3[och * 32 + t];
            #pragma unroll
            for (int c = 0; c < 16; ++c) v += lds[c * 32 + t];
            h3[b * 512 + och * 32 + t] = fmaxf(v, 0.f);
        }
    }
    gridbar(bar, 3, TAIL_BLKS);

    // ---- P4: out = h3 @ w4 + b4.  blocks 0..7 (b), 2 outputs each
    if (blk < 8) {
        int b = blk;
        int o = t >> 8, kl = t & 255;        // k pair = kl*2, kl*2+1
        float acc = h3[b * 512 + kl * 2] * w4p[(kl * 2) * 2 + o]
                  + h3[b * 512 + kl * 2 + 1] * w4p[(kl * 2 + 1) * 2 + o];
        lds[t] = acc;
        __syncthreads();
        for (int st = 128; st > 0; st >>= 1) {
            if (kl < st) lds[o * 256 + kl] += lds[o * 256 + kl + st];
            __syncthreads();
        }
        if (t == 0) {
            out[b * 2 + 0] = lds[0] + b4p[0];
            out[b * 2 + 1] = lds[256] + b4p[1];
        }
    }
}

extern "C" void kernel_launch(void* const* d_in, const int* in_sizes, int n_in,
                              void* d_out, int out_size, void* d_ws, size_t ws_size,
                              hipStream_t stream)
{
    const float* smi_tf   = (const float*)d_in[0];
    const float* pro_tf   = (const float*)d_in[1];
    const float* drug_gat = (const float*)d_in[2];
    const float* w_att    = (const float*)d_in[3];
    const float* b_att    = (const float*)d_in[4];
    const float* w1 = (const float*)d_in[5];
    const float* b1 = (const float*)d_in[6];
    const float* w2 = (const float*)d_in[7];
    const float* b2 = (const float*)d_in[8];
    const float* w3 = (const float*)d_in[9];
    const float* b3 = (const float*)d_in[10];
    const float* w4 = (const float*)d_in[11];
    const float* b4 = (const float*)d_in[12];
    float* out = (float*)d_out;

    float* ws = (float*)d_ws;
    float* smi_attss = ws;                   // 74240
    float* pro_att   = smi_attss + 74240;    // 512000
    float* smi_tfs   = pro_att + 512000;     // 74240
    float* pro_tfs   = smi_tfs + 74240;      // 512000
    float* x   = pro_tfs + 512000;           // 1024
    float* h1  = x + 1024;                   // 8192
    float* h2  = h1 + 8192;                  // 8192
    float* h3  = h2 + 8192;                  // 4096
    int*   bar = (int*)(h3 + 4096);          // 16 ints

    k_proj2<<<B * PROJ_BPB, 256, 0, stream>>>(smi_tf, pro_tf, drug_gat, w_att, b_att,
                                              smi_attss, pro_att, bar);
    k_pair <<<PAIR_BLKS, 512, 0, stream>>>((const float4*)smi_attss, (const float4*)pro_att,
                                           smi_attss, pro_tf, w_att, b_att, smi_tfs, pro_tfs);
    k_tail <<<TAIL_BLKS, 512, 0, stream>>>((const float4*)smi_tfs, (const float4*)pro_tfs,
                                           w1, b1, w2, b2, w3, b3, w4, b4,
                                           x, h1, h2, h3, bar, out);
}